// Round 12
// baseline (119.679 us; speedup 1.0000x reference)
//
#include <hip/hip_runtime.h>

#define PNUM 128
#define BATCH 8192
#define GRID1 (BATCH / 4)            // 4 batches per block -> 2048 blocks

typedef _Float16 h2 __attribute__((ext_vector_type(2)));
typedef _Float16 h4 __attribute__((ext_vector_type(4)));
typedef _Float16 h8 __attribute__((ext_vector_type(8)));

__device__ __forceinline__ h2 cvt2(float x, float y) {
    return __builtin_bit_cast(h2, __builtin_amdgcn_cvt_pkrtz(x, y));
}
__device__ __forceinline__ h4 cvt4(float4 v) {
    h2 a = cvt2(v.x, v.y), b = cvt2(v.z, v.w);
    return (h4){a.x, a.y, b.x, b.y};
}

// Packed smooth-L1 term, both coords, f32-accumulated. 5 packed VALU ops:
// v_pk_add, v_and_b32 (|d|), v_pk_min, v_pk_fma, v_dot2_f32_f16.
__device__ __forceinline__ void unit(h2 p, h2 q, float& acc) {
    h2 d = p - q;
    h2 a = __builtin_bit_cast(h2, __builtin_bit_cast(unsigned, d) & 0x7fff7fffu);
    h2 m = __builtin_elementwise_min(a, (h2)(_Float16)1.0f);
    h2 t = __builtin_elementwise_fma(m, (h2)(_Float16)-0.5f, a);
    acc = __builtin_amdgcn_fdot2(m, t, acc, false);
}

__device__ __forceinline__ h2 lo2(h4 v) { return __builtin_shufflevector(v, v, 0, 1); }
__device__ __forceinline__ h2 hi2(h4 v) { return __builtin_shufflevector(v, v, 2, 3); }
__device__ __forceinline__ h4 lo4(h8 v) { return __builtin_shufflevector(v, v, 0, 1, 2, 3); }
__device__ __forceinline__ h4 hi4(h8 v) { return __builtin_shufflevector(v, v, 4, 5, 6, 7); }
__device__ __forceinline__ h2 el2(h8 v, int i) { return (h2){v[2 * i], v[2 * i + 1]}; }

// Block = 256 threads = 4 waves = 2 batch-pairs x 2 K-splits.
// Wave (pair, sK): j in [64*sK, 64*sK+64) for BOTH batches of its pair
// (one batch per 32-lane half; lane kk owns shifts 4kk..4kk+3).
// Per hh (4 j): 1 lane-dense gather b128 + 2 half-uniform pred b128 = 3 DS.
// Both K-waves stage identical ring/pred data (benign same-value race;
// own-wave lgkmcnt ordering -> no barrier before the loop).
// K-combine: sK=1 spills 8 partials to LDS, one barrier, sK=0 adds+reduces.
__global__ __launch_bounds__(256, 8) void match_fused(
        const float* __restrict__ pred0,
        const float* __restrict__ pred1,
        const float* __restrict__ gt,
        float* __restrict__ out) {
    __shared__ __align__(16) h4 ring [4][128];      // doubled gt ring, 1 KB/batch
    __shared__ __align__(16) h4 preds[4][2][64];    // pred rows, .5 KB each
    __shared__ float part[2][8][64];                // sK=1 partials, 4 KB

    const int t    = threadIdx.x;
    const int k    = t & 63;
    const int w    = __builtin_amdgcn_readfirstlane(t >> 6);
    const int pair = w >> 1;
    const int sK   = w & 1;
    const int h    = k >> 5;                 // which batch of the pair
    const int kk   = k & 31;                 // owns shifts 4kk..4kk+3
    const int bb   = 2 * pair + h;
    const int b    = blockIdx.x * 4 + bb;

    h4* ring4 = ring[bb];
    h4* q0 = preds[bb][0];
    h4* q1 = preds[bb][1];

    // ---- redundant staging (both K-waves write identical values) ----
    const float4* gv4 = (const float4*)(gt    + (size_t)b * (PNUM * 2));
    const float4* p0v = (const float4*)(pred0 + (size_t)b * (PNUM * 2));
    const float4* p1v = (const float4*)(pred1 + (size_t)b * (PNUM * 2));
    {
        h4 v = cvt4(gv4[kk]);      ring4[kk]      = v; ring4[kk + 64] = v;
        v    = cvt4(gv4[kk + 32]); ring4[kk + 32] = v; ring4[kk + 96] = v;
        q0[kk]      = cvt4(p0v[kk]);
        q0[kk + 32] = cvt4(p0v[kk + 32]);
        q1[kk]      = cvt4(p1v[kk]);
        q1[kk + 32] = cvt4(p1v[kk + 32]);
    }

    const h8* q0_8 = (const h8*)q0;          // 32 entries of 4 points
    const h8* q1_8 = (const h8*)q1;

    const int h0 = 16 * sK;                  // this wave's hh range
    h8 wi = *(const h8*)&ring4[2 * kk + 32 * sK];   // window @ j = 64*sK
    h4 w0 = lo4(wi), w1 = hi4(wi);

    float r00 = 0.f, r01 = 0.f, r02 = 0.f, r03 = 0.f;   // pred0, shifts 4kk+0..3
    float r10 = 0.f, r11 = 0.f, r12 = 0.f, r13 = 0.f;   // pred1

#pragma unroll 4
    for (int hh = h0; hh < h0 + 16; ++hh) {
        h8 n  = *(const h8*)&ring4[2 * kk + 2 * hh + 2];  // 4 new points (b128)
        h8 P0 = q0_8[hh];                                  // pred pts 4hh..4hh+3
        h8 P1 = q1_8[hh];
        h4 w2 = lo4(n), w3 = hi4(n);

        h2 A0 = lo2(w0), A1 = hi2(w0), A2 = lo2(w1), A3 = hi2(w1);
        h2 A4 = lo2(w2), A5 = hi2(w2), A6 = lo2(w3);
        h2 p0a = el2(P0, 0), p0b = el2(P0, 1), p0c = el2(P0, 2), p0d = el2(P0, 3);
        h2 p1a = el2(P1, 0), p1b = el2(P1, 1), p1c = el2(P1, 2), p1d = el2(P1, 3);

        unit(p0a, A0, r00); unit(p0b, A1, r00); unit(p0c, A2, r00); unit(p0d, A3, r00);
        unit(p0a, A1, r01); unit(p0b, A2, r01); unit(p0c, A3, r01); unit(p0d, A4, r01);
        unit(p0a, A2, r02); unit(p0b, A3, r02); unit(p0c, A4, r02); unit(p0d, A5, r02);
        unit(p0a, A3, r03); unit(p0b, A4, r03); unit(p0c, A5, r03); unit(p0d, A6, r03);

        unit(p1a, A0, r10); unit(p1b, A1, r10); unit(p1c, A2, r10); unit(p1d, A3, r10);
        unit(p1a, A1, r11); unit(p1b, A2, r11); unit(p1c, A3, r11); unit(p1d, A4, r11);
        unit(p1a, A2, r12); unit(p1b, A3, r12); unit(p1c, A4, r12); unit(p1d, A5, r12);
        unit(p1a, A3, r13); unit(p1b, A4, r13); unit(p1c, A5, r13); unit(p1d, A6, r13);

        w0 = w2; w1 = w3;
    }

    // ---- K-split combine ----
    if (sK) {                                // lane-dense b32 writes, conflict-free
        float* pp = &part[pair][0][k];
        pp[0]       = r00; pp[64]      = r01; pp[2 * 64] = r02; pp[3 * 64] = r03;
        pp[4 * 64]  = r10; pp[5 * 64]  = r11; pp[6 * 64] = r12; pp[7 * 64] = r13;
    }
    __syncthreads();

    float s2 = 0.f;
    if (!sK) {
        const float* pp = &part[pair][0][k];
        r00 += pp[0];       r01 += pp[64];      r02 += pp[2 * 64]; r03 += pp[3 * 64];
        r10 += pp[4 * 64];  r11 += pp[5 * 64];  r12 += pp[6 * 64]; r13 += pp[7 * 64];

        float m0 = fminf(fminf(r00, r01), fminf(r02, r03));
        float m1 = fminf(fminf(r10, r11), fminf(r12, r13));
#pragma unroll
        for (int m = 16; m > 0; m >>= 1) {   // min within each 32-lane half
            m0 = fminf(m0, __shfl_xor(m0, m, 64));
            m1 = fminf(m1, __shfl_xor(m1, m, 64));
        }
        s2 = m0 + m1;                        // this batch's min0+min1
        s2 += __shfl_xor(s2, 32, 64);        // + the pair's other batch
    }

    __shared__ float bsum[2];
    if (!sK && k == 0) bsum[pair] = s2;
    __syncthreads();
    if (t == 0) {
        // relaxed device-scope atomic; NO fence (R5: fences -> writeback storm)
        atomicAdd(out, (bsum[0] + bsum[1]) * (1.0f / (2.0f * BATCH * PNUM)));
    }
}

extern "C" void kernel_launch(void* const* d_in, const int* in_sizes, int n_in,
                              void* d_out, int out_size, void* d_ws, size_t ws_size,
                              hipStream_t stream) {
    const float* pred0 = (const float*)d_in[0];
    const float* pred1 = (const float*)d_in[1];
    const float* gt    = (const float*)d_in[2];
    float* out = (float*)d_out;

    (void)hipMemsetAsync(out, 0, sizeof(float), stream);   // out is 0xAA-poisoned
    match_fused<<<GRID1, 256, 0, stream>>>(pred0, pred1, gt, out);
}